// Round 2
// baseline (529.338 us; speedup 1.0000x reference)
//
#include <hip/hip_runtime.h>
#include <hip/hip_bf16.h>
#include <stdint.h>

#define TOK   16384
#define DIM   256
#define HIDN  1024
#define OUTD  256
#define NEXP  8
#define NSH   3
#define TM    32

typedef short bf16x8  __attribute__((ext_vector_type(8)));
typedef float f32x4   __attribute__((ext_vector_type(4)));
typedef short short4v __attribute__((ext_vector_type(4)));

// ---- workspace layout (bytes, all 256-aligned) ----
constexpr size_t XB_OFF   = 0;                                        // T*D bf16
constexpr size_t W1P_OFF  = XB_OFF  + (size_t)TOK*DIM*2;              // 11*D*HID bf16 packed
constexpr size_t W2P_OFF  = W1P_OFF + (size_t)(NSH+NEXP)*DIM*HIDN*2;  // 11*HID*O bf16 packed
constexpr size_t WTS_OFF  = W2P_OFF + (size_t)(NSH+NEXP)*HIDN*OUTD*2; // T*2 fp32 (0.5-scaled)
constexpr size_t IDS_OFF  = WTS_OFF + (size_t)TOK*2*4;                // T*2 int32
constexpr size_t CNT_OFF  = IDS_OFF + (size_t)TOK*2*4;                // E int32 (+pad)
constexpr size_t LTOK_OFF = CNT_OFF + 256;                            // E*T int32
constexpr size_t LW_OFF   = LTOK_OFF + (size_t)NEXP*TOK*4;            // E*T fp32
constexpr size_t WS_NEED  = LW_OFF + (size_t)NEXP*TOK*4;

__device__ __forceinline__ unsigned short f2bf(float f) {
    __hip_bfloat16 h = __float2bfloat16(f);
    return *reinterpret_cast<unsigned short*>(&h);
}

__device__ __forceinline__ f32x4 mfma16(bf16x8 a, bf16x8 b, f32x4 c) {
    return __builtin_amdgcn_mfma_f32_16x16x32_bf16(a, b, c, 0, 0, 0);
}

// XOR-swizzled byte offset into the 32x1024 bf16 H tile (row stride 2048B).
// Breaks the 16-way bank conflict of column-slice ds_read_b128 (guide G4).
__device__ __forceinline__ int hswz(int row, int col) {
    int b = (row << 11) + (col << 1);
    return b ^ ((row & 7) << 4);
}

// ---- fp32 -> bf16 of X, row-major preserved ----
__global__ void k_convert_x(const float* __restrict__ x, short* __restrict__ xb) {
    int i = blockIdx.x * 256 + threadIdx.x;             // 4 elems per thread
    float4 v = reinterpret_cast<const float4*>(x)[i];
    short4v o;
    o[0] = (short)f2bf(v.x); o[1] = (short)f2bf(v.y);
    o[2] = (short)f2bf(v.z); o[3] = (short)f2bf(v.w);
    reinterpret_cast<short4v*>(xb)[i] = o;
}

// ---- fp32 weights -> bf16 packed in MFMA B-fragment order ----
// packed elem offset = ((kt*NT + nt)*64 + lane)*8 + j ; lane: n=nt*16+(lane&15),
// k = kt*32 + 8*(lane>>4) + j. One thread = one 8-elem fragment group (16B store).
__global__ void k_convert_w(const float* __restrict__ sw1, const float* __restrict__ iw1,
                            const float* __restrict__ sw2, const float* __restrict__ iw2,
                            short* __restrict__ w1p, short* __restrict__ w2p) {
    int gid = blockIdx.x * 256 + threadIdx.x;
    const int G1 = (NSH+NEXP) * (DIM/32) * (HIDN/16) * 64;   // 360448
    bool isW1 = gid < G1;
    int g = isW1 ? gid : gid - G1;
    int lane = g & 63;
    int gg = g >> 6;
    int NT = isW1 ? (HIDN/16) : (OUTD/16);
    int KT = isW1 ? (DIM/32)  : (HIDN/32);
    int nt = gg % NT; gg /= NT;
    int kt = gg % KT;
    int slot = gg / KT;
    int k = kt*32 + ((lane >> 4) << 3);
    int n = nt*16 + (lane & 15);
    int Nd = isW1 ? HIDN : OUTD;
    const float* src;
    if (isW1) src = (slot < NSH) ? sw1 + (size_t)slot*DIM*HIDN  : iw1 + (size_t)(slot-NSH)*DIM*HIDN;
    else      src = (slot < NSH) ? sw2 + (size_t)slot*HIDN*OUTD : iw2 + (size_t)(slot-NSH)*HIDN*OUTD;
    bf16x8 o;
    #pragma unroll
    for (int j = 0; j < 8; ++j) o[j] = (short)f2bf(src[(size_t)(k + j)*Nd + n]);
    short* dst = isW1 ? w1p : w2p;
    reinterpret_cast<bf16x8*>(dst)[g] = o;
}

// ---- gating: fp32-exact logits, top-2, renormalized, pre-scaled by 0.5 ----
__global__ void k_gate(const float* __restrict__ x, const float* __restrict__ gw,
                       const float* __restrict__ gb, float* __restrict__ wts,
                       int* __restrict__ ids) {
    int wid = threadIdx.x >> 6, lane = threadIdx.x & 63;
    int t = blockIdx.x * 4 + wid;
    const float* xr = x + (size_t)t * DIM;
    float acc[NEXP] = {0.f,0.f,0.f,0.f,0.f,0.f,0.f,0.f};
    #pragma unroll
    for (int i = 0; i < DIM/64; ++i) {
        int d = i*64 + lane;
        float xv = xr[d];
        const float* g = gw + (size_t)d * NEXP;
        #pragma unroll
        for (int e = 0; e < NEXP; ++e) acc[e] = fmaf(xv, g[e], acc[e]);
    }
    #pragma unroll
    for (int off = 32; off; off >>= 1) {
        #pragma unroll
        for (int e = 0; e < NEXP; ++e) acc[e] += __shfl_xor(acc[e], off, 64);
    }
    if (lane == 0) {
        float l[NEXP];
        #pragma unroll
        for (int e = 0; e < NEXP; ++e) l[e] = acc[e] + gb[e];
        int e0 = 0; float v0 = l[0];
        #pragma unroll
        for (int e = 1; e < NEXP; ++e) if (l[e] > v0) { v0 = l[e]; e0 = e; }
        int e1 = -1; float v1 = -1e30f;
        #pragma unroll
        for (int e = 0; e < NEXP; ++e) if (e != e0 && l[e] > v1) { v1 = l[e]; e1 = e; }
        float r = expf(v1 - v0);              // <= 1
        float w0 = 0.5f / (1.f + r);
        float w1 = 0.5f * r / (1.f + r);
        ids[2*t]   = e0;  ids[2*t+1] = e1;
        wts[2*t]   = w0;  wts[2*t+1] = w1;
    }
}

// ---- build per-expert token lists (fixed capacity T per expert, no scan) ----
__global__ void k_route(const int* __restrict__ ids, const float* __restrict__ wts,
                        int* __restrict__ cnt, int* __restrict__ ltok,
                        float* __restrict__ lw) {
    int t = blockIdx.x * 256 + threadIdx.x;
    #pragma unroll
    for (int k = 0; k < 2; ++k) {
        int e = ids[2*t + k];
        int p = atomicAdd(&cnt[e], 1);
        ltok[(size_t)e*TOK + p] = t;
        lw  [(size_t)e*TOK + p] = wts[2*t + k];
    }
}

// ---- shared experts: 32 tokens/block, 3 experts fused, acc across experts ----
__global__ __launch_bounds__(512) void k_shared(
    const short* __restrict__ xb, const short* __restrict__ w1p, const short* __restrict__ w2p,
    const float* __restrict__ sb1, const float* __restrict__ sb2,
    const float* __restrict__ obj, float* __restrict__ out)
{
    __shared__ short Hl[TM * HIDN];                    // 64 KB, swizzled
    const int t0   = blockIdx.x * TM;
    const int wid  = threadIdx.x >> 6;
    const int lane = threadIdx.x & 63;
    const int lrow = lane & 15;
    const int lk8  = (lane >> 4) << 3;
    const int rbase = (lane >> 4) << 2;
    char* hb = reinterpret_cast<char*>(Hl);

    f32x4 acc2[2][2] = {};
    for (int s = 0; s < NSH; ++s) {
        const short* W1 = w1p + (size_t)s * DIM * HIDN;
        const short* W2 = w2p + (size_t)s * HIDN * OUTD;
        // stage 1: H[32 x 1024], wave owns 128-col slice
        f32x4 acc1[2][8] = {};
        for (int kt = 0; kt < DIM/32; ++kt) {
            bf16x8 a[2];
            #pragma unroll
            for (int m = 0; m < 2; ++m) {
                int t = t0 + m*16 + lrow;
                a[m] = *reinterpret_cast<const bf16x8*>(xb + (size_t)t*DIM + kt*32 + lk8);
            }
            #pragma unroll
            for (int ntl = 0; ntl < 8; ++ntl) {
                int nt = wid*8 + ntl;
                bf16x8 b = *reinterpret_cast<const bf16x8*>(W1 + ((size_t)(kt*(HIDN/16) + nt)*64 + lane)*8);
                acc1[0][ntl] = mfma16(a[0], b, acc1[0][ntl]);
                acc1[1][ntl] = mfma16(a[1], b, acc1[1][ntl]);
            }
        }
        __syncthreads();   // prior stage-2 readers done before overwrite
        #pragma unroll
        for (int ntl = 0; ntl < 8; ++ntl) {
            int col = wid*128 + ntl*16 + lrow;
            float bias = sb1[s*HIDN + col];
            #pragma unroll
            for (int m = 0; m < 2; ++m) {
                #pragma unroll
                for (int r = 0; r < 4; ++r) {
                    int row = m*16 + rbase + r;
                    float tw = 0.5f * obj[(size_t)(t0 + row)*NSH + s];
                    float v = fmaxf(acc1[m][ntl][r] + bias, 0.f) * tw;
                    *reinterpret_cast<unsigned short*>(hb + hswz(row, col)) = f2bf(v);
                }
            }
        }
        __syncthreads();
        // stage 2: O[32 x 256], wave owns 32-col slice; accumulates across s
        for (int kt = 0; kt < HIDN/32; ++kt) {
            bf16x8 a[2];
            #pragma unroll
            for (int m = 0; m < 2; ++m) {
                int row = m*16 + lrow;
                a[m] = *reinterpret_cast<const bf16x8*>(hb + hswz(row, kt*32 + lk8));
            }
            #pragma unroll
            for (int n = 0; n < 2; ++n) {
                int nt = wid*2 + n;
                bf16x8 b = *reinterpret_cast<const bf16x8*>(W2 + ((size_t)(kt*(OUTD/16) + nt)*64 + lane)*8);
                acc2[0][n] = mfma16(a[0], b, acc2[0][n]);
                acc2[1][n] = mfma16(a[1], b, acc2[1][n]);
            }
        }
    }
    // epilogue: + sum_s 0.5*obj*b2, non-atomic write (first writer of out)
    #pragma unroll
    for (int m = 0; m < 2; ++m)
        #pragma unroll
        for (int n = 0; n < 2; ++n) {
            int col = wid*32 + n*16 + lrow;
            #pragma unroll
            for (int r = 0; r < 4; ++r) {
                int row = m*16 + rbase + r;
                int t = t0 + row;
                float v = acc2[m][n][r];
                #pragma unroll
                for (int s = 0; s < NSH; ++s)
                    v += 0.5f * obj[(size_t)t*NSH + s] * sb2[s*OUTD + col];
                out[(size_t)t*OUTD + col] = v;
            }
        }
}

// ---- independent experts: gathered 32-token chunks per expert, atomicAdd ----
// NOTE: lw is ALREADY 0.5-scaled by k_gate — do NOT scale again here.
__global__ __launch_bounds__(512) void k_ind(
    const short* __restrict__ xb, const short* __restrict__ w1p, const short* __restrict__ w2p,
    const float* __restrict__ ib1, const float* __restrict__ ib2,
    const int* __restrict__ cnt, const int* __restrict__ ltok, const float* __restrict__ lw,
    float* __restrict__ out)
{
    __shared__ short Hl[TM * HIDN];
    const int e  = blockIdx.y;
    const int n0 = blockIdx.x * TM;
    const int count = cnt[e];
    if (n0 >= count) return;
    const short* W1 = w1p + (size_t)(NSH + e) * DIM * HIDN;
    const short* W2 = w2p + (size_t)(NSH + e) * HIDN * OUTD;
    const int wid  = threadIdx.x >> 6;
    const int lane = threadIdx.x & 63;
    const int lrow = lane & 15;
    const int lk8  = (lane >> 4) << 3;
    const int rbase = (lane >> 4) << 2;
    char* hb = reinterpret_cast<char*>(Hl);

    int tokA[2];
    #pragma unroll
    for (int m = 0; m < 2; ++m) {
        int p = n0 + m*16 + lrow;
        tokA[m] = ltok[(size_t)e*TOK + min(p, count-1)];
    }
    f32x4 acc1[2][8] = {};
    for (int kt = 0; kt < DIM/32; ++kt) {
        bf16x8 a[2];
        #pragma unroll
        for (int m = 0; m < 2; ++m)
            a[m] = *reinterpret_cast<const bf16x8*>(xb + (size_t)tokA[m]*DIM + kt*32 + lk8);
        #pragma unroll
        for (int ntl = 0; ntl < 8; ++ntl) {
            int nt = wid*8 + ntl;
            bf16x8 b = *reinterpret_cast<const bf16x8*>(W1 + ((size_t)(kt*(HIDN/16) + nt)*64 + lane)*8);
            acc1[0][ntl] = mfma16(a[0], b, acc1[0][ntl]);
            acc1[1][ntl] = mfma16(a[1], b, acc1[1][ntl]);
        }
    }
    #pragma unroll
    for (int ntl = 0; ntl < 8; ++ntl) {
        int col = wid*128 + ntl*16 + lrow;
        float bias = ib1[(size_t)e*HIDN + col];
        #pragma unroll
        for (int m = 0; m < 2; ++m) {
            #pragma unroll
            for (int r = 0; r < 4; ++r) {
                int row = m*16 + rbase + r;
                int p = n0 + row;
                float tw = (p < count) ? lw[(size_t)e*TOK + p] : 0.f;   // lw already 0.5-scaled
                float v = fmaxf(acc1[m][ntl][r] + bias, 0.f) * tw;
                *reinterpret_cast<unsigned short*>(hb + hswz(row, col)) = f2bf(v);
            }
        }
    }
    __syncthreads();
    f32x4 acc2[2][2] = {};
    for (int kt = 0; kt < HIDN/32; ++kt) {
        bf16x8 a[2];
        #pragma unroll
        for (int m = 0; m < 2; ++m) {
            int row = m*16 + lrow;
            a[m] = *reinterpret_cast<const bf16x8*>(hb + hswz(row, kt*32 + lk8));
        }
        #pragma unroll
        for (int n = 0; n < 2; ++n) {
            int nt = wid*2 + n;
            bf16x8 b = *reinterpret_cast<const bf16x8*>(W2 + ((size_t)(kt*(OUTD/16) + nt)*64 + lane)*8);
            acc2[0][n] = mfma16(a[0], b, acc2[0][n]);
            acc2[1][n] = mfma16(a[1], b, acc2[1][n]);
        }
    }
    #pragma unroll
    for (int m = 0; m < 2; ++m)
        #pragma unroll
        for (int n = 0; n < 2; ++n) {
            int col = wid*32 + n*16 + lrow;
            #pragma unroll
            for (int r = 0; r < 4; ++r) {
                int row = m*16 + rbase + r;
                int p = n0 + row;
                if (p < count) {
                    int t = ltok[(size_t)e*TOK + p];
                    float v = acc2[m][n][r] + lw[(size_t)e*TOK + p] * ib2[(size_t)e*OUTD + col];
                    atomicAdd(&out[(size_t)t*OUTD + col], v);
                }
            }
        }
}

extern "C" void kernel_launch(void* const* d_in, const int* in_sizes, int n_in,
                              void* d_out, int out_size, void* d_ws, size_t ws_size,
                              hipStream_t stream) {
    const float* x   = (const float*)d_in[0];
    const float* obj = (const float*)d_in[1];
    const float* gw  = (const float*)d_in[2];
    const float* gb  = (const float*)d_in[3];
    const float* sw1 = (const float*)d_in[4];
    const float* sb1 = (const float*)d_in[5];
    const float* sw2 = (const float*)d_in[6];
    const float* sb2 = (const float*)d_in[7];
    const float* iw1 = (const float*)d_in[8];
    const float* ib1 = (const float*)d_in[9];
    const float* iw2 = (const float*)d_in[10];
    const float* ib2 = (const float*)d_in[11];
    float* out = (float*)d_out;
    char* ws = (char*)d_ws;
    if (ws_size < WS_NEED) return;   // workspace too small -> visible as validation failure

    short* xb   = (short*)(ws + XB_OFF);
    short* w1p  = (short*)(ws + W1P_OFF);
    short* w2p  = (short*)(ws + W2P_OFF);
    float* wts  = (float*)(ws + WTS_OFF);
    int*   ids  = (int*)  (ws + IDS_OFF);
    int*   cnt  = (int*)  (ws + CNT_OFF);
    int*   ltok = (int*)  (ws + LTOK_OFF);
    float* lwt  = (float*)(ws + LW_OFF);

    hipMemsetAsync(ws + CNT_OFF, 0, 256, stream);
    k_convert_x<<<(TOK*DIM/4)/256, 256, 0, stream>>>(x, xb);
    {
        const int G = (NSH+NEXP) * ((DIM/32)*(HIDN/16) + (HIDN/32)*(OUTD/16)) * 64; // 720896
        k_convert_w<<<G/256, 256, 0, stream>>>(sw1, iw1, sw2, iw2, w1p, w2p);
    }
    k_gate<<<TOK/4, 256, 0, stream>>>(x, gw, gb, wts, ids);
    k_route<<<TOK/256, 256, 0, stream>>>(ids, wts, cnt, ltok, lwt);
    k_shared<<<TOK/TM, 512, 0, stream>>>(xb, w1p, w2p, sb1, sb2, obj, out);
    k_ind<<<dim3(TOK/TM, NEXP), 512, 0, stream>>>(xb, w1p, w2p, ib1, ib2, cnt, ltok, lwt, out);
}